// Round 1
// baseline (156.231 us; speedup 1.0000x reference)
//
#include <hip/hip_runtime.h>

// GAGKNNQueryAndGroup: B=4, N=8192, NPOINT=2048, C=64, NSAMPLE=32, LAMBDA=0.5
// Inputs: xyz(B,N,3) f32 | new_xyz(B,NPOINT,3) f32 | components(B,N,1) int |
//         new_components(B,NPOINT,1) int | features(B,C,N) f32
// Output: (B, 3+C, NPOINT, NS) f32
//
// NOTE: LAMBDA == 0.5 makes the component mask numerically irrelevant:
// where(mask, d*0.5, d*0.5) == d*0.5 (exact, order-preserving). Components unused.

#define BQ 4
#define NN_ 8192
#define NPOINT 2048
#define CF 64
#define NS 32
#define T1 256
#define PER (NN_ / T1)   // 32 candidates per thread
#define CAP 1024         // candidate list capacity (expected ~34)

// ---------------- Phase 1: exact top-32 selection per query ----------------
__global__ __launch_bounds__(256) void knn_kernel(const float* __restrict__ xyz,
                                                  const float* __restrict__ new_xyz,
                                                  int* __restrict__ idxOut) {
  const int q = blockIdx.x;            // b*NPOINT + p
  const int b = q / NPOINT;
  const int tid = threadIdx.x;

  const float qx = new_xyz[q * 3 + 0];
  const float qy = new_xyz[q * 3 + 1];
  const float qz = new_xyz[q * 3 + 2];

  const float* __restrict__ base = xyz + (size_t)b * NN_ * 3;

  float d[PER];
  float lmin = 3.4e38f;
  int n = tid;
#pragma unroll
  for (int j = 0; j < PER; j++, n += T1) {
    float dx = base[n * 3 + 0] - qx;
    float dy = base[n * 3 + 1] - qy;
    float dz = base[n * 3 + 2] - qz;
    // Match numpy f32 evaluation exactly: no FMA contraction, left-to-right sum.
    float dist = __fadd_rn(__fadd_rn(__fmul_rn(dx, dx), __fmul_rn(dy, dy)),
                           __fmul_rn(dz, dz));
    dist *= 0.5f;   // LAMBDA == 1-LAMBDA == 0.5
    d[j] = dist;
    lmin = fminf(lmin, dist);
  }

  // theta = 32nd smallest of the 256 per-thread minima: a guaranteed upper
  // bound on the true 32nd-smallest distance (those 32 mins are 32 distinct
  // data values themselves).
  __shared__ float mins[T1];
  mins[tid] = lmin;
  __syncthreads();
  for (int k = 2; k <= T1; k <<= 1) {
    for (int j = k >> 1; j > 0; j >>= 1) {
      int ixj = tid ^ j;
      if (ixj > tid) {
        float a = mins[tid], bb = mins[ixj];
        bool up = ((tid & k) == 0);
        if (up ? (a > bb) : (a < bb)) { mins[tid] = bb; mins[ixj] = a; }
      }
      __syncthreads();
    }
  }
  const float theta = mins[NS - 1];

  // Collect all candidates with d <= theta (expected ~34, guaranteed >= 32).
  __shared__ unsigned long long cand[CAP];
  __shared__ int cnt;
  if (tid == 0) cnt = 0;
  __syncthreads();
  n = tid;
#pragma unroll
  for (int j = 0; j < PER; j++, n += T1) {
    if (d[j] <= theta) {
      int pos = atomicAdd(&cnt, 1);
      if (pos < CAP)
        cand[pos] = ((unsigned long long)__float_as_uint(d[j]) << 32) | (unsigned)n;
    }
  }
  __syncthreads();
  int m = cnt < CAP ? cnt : CAP;

  // Exact rank of each candidate by (dist_bits, idx) — matches stable argsort.
  for (int i = tid; i < m; i += T1) {
    unsigned long long x = cand[i];
    int r = 0;
    for (int j = 0; j < m; j++) r += (cand[j] < x) ? 1 : 0;
    if (r < NS) idxOut[q * NS + r] = (int)(x & 0xffffffffu);
  }
}

// ---------------- Phase 2: features (B,C,N) -> featsT (B,N,C) ----------------
__global__ __launch_bounds__(256) void transpose_kernel(const float* __restrict__ f,
                                                        float* __restrict__ ft) {
  __shared__ float t[32][33];
  const int b = blockIdx.z;
  const int n0 = blockIdx.x * 32;
  const int c0 = blockIdx.y * 32;
  const int tx = threadIdx.x;   // 0..31
  const int ty = threadIdx.y;   // 0..7
#pragma unroll
  for (int i = 0; i < 4; i++) {
    int c = c0 + ty + i * 8;
    t[ty + i * 8][tx] = f[(size_t)b * CF * NN_ + (size_t)c * NN_ + n0 + tx];
  }
  __syncthreads();
#pragma unroll
  for (int i = 0; i < 4; i++) {
    int nrow = n0 + ty + i * 8;
    ft[(size_t)b * NN_ * CF + (size_t)nrow * CF + c0 + tx] = t[tx][ty + i * 8];
  }
}

// ---------------- Phase 3: gather + grouped write ----------------
#define FSTR 68   // LDS row stride: multiple of 4 (float4 stores), 4-way bank alias only
__global__ __launch_bounds__(256) void group_kernel(const float* __restrict__ xyz,
                                                    const float* __restrict__ new_xyz,
                                                    const float* __restrict__ featsT,
                                                    const int* __restrict__ idxArr,
                                                    float* __restrict__ out) {
  const int q = blockIdx.x;            // b*NPOINT + p
  const int b = q / NPOINT;
  const int p = q - b * NPOINT;
  const int tid = threadIdx.x;

  __shared__ int sIdx[NS];
  __shared__ __align__(16) float ldsF[NS * FSTR];
  __shared__ float ldsX[3 * NS];

  if (tid < NS) sIdx[tid] = idxArr[q * NS + tid];
  __syncthreads();

  {
    // 256 threads = 32 samples x 8 readers; each reader pulls 32B of the
    // 256B contiguous feature row for its sample.
    int s = tid >> 3, r = tid & 7;
    int nn = sIdx[s];
    const float4* src = (const float4*)(featsT + ((size_t)b * NN_ + nn) * CF);
    float4 v0 = src[r * 2];
    float4 v1 = src[r * 2 + 1];
    float4* dst = (float4*)(ldsF + s * FSTR + r * 8);
    dst[0] = v0;
    dst[1] = v1;
  }
  if (tid < 96) {
    int dd = tid >> 5, s = tid & 31;
    int nn = sIdx[s];
    ldsX[dd * NS + s] = xyz[((size_t)b * NN_ + nn) * 3 + dd] -
                        new_xyz[(size_t)q * 3 + dd];
  }
  __syncthreads();

  // Write 67 rows of 32 floats (128B coalesced per row), 8 rows at a time.
  const int s = tid & 31;
  const int r0 = tid >> 5;
#pragma unroll
  for (int k = 0; k < 9; k++) {
    int row = r0 + k * 8;
    if (row < 67) {
      float v = (row < 3) ? ldsX[row * NS + s] : ldsF[s * FSTR + (row - 3)];
      out[(((size_t)b * 67 + row) * NPOINT + p) * NS + s] = v;
    }
  }
}

extern "C" void kernel_launch(void* const* d_in, const int* in_sizes, int n_in,
                              void* d_out, int out_size, void* d_ws, size_t ws_size,
                              hipStream_t stream) {
  const float* xyz      = (const float*)d_in[0];   // (4,8192,3)
  const float* new_xyz  = (const float*)d_in[1];   // (4,2048,3)
  // d_in[2], d_in[3]: components — unused (LAMBDA=0.5 makes mask a no-op)
  const float* features = (const float*)d_in[4];   // (4,64,8192)
  float* out = (float*)d_out;

  // workspace layout: [idx: 4*2048*32 int = 1MB][featsT: 4*8192*64 f32 = 8MB]
  int* idxArr = (int*)d_ws;
  float* featsT = (float*)((char*)d_ws + (size_t)BQ * NPOINT * NS * sizeof(int));

  knn_kernel<<<BQ * NPOINT, T1, 0, stream>>>(xyz, new_xyz, idxArr);
  transpose_kernel<<<dim3(NN_ / 32, CF / 32, BQ), dim3(32, 8), 0, stream>>>(features, featsT);
  group_kernel<<<BQ * NPOINT, T1, 0, stream>>>(xyz, new_xyz, featsT, idxArr, out);
}